// Round 1
// baseline (12651.197 us; speedup 1.0000x reference)
//
#include <hip/hip_runtime.h>
#include <cstdint>
#include <cstddef>

typedef short short8 __attribute__((ext_vector_type(8)));
typedef float floatx4 __attribute__((ext_vector_type(4)));

static constexpr int TT = 256;   // time steps
static constexpr int BB = 256;   // batch
static constexpr int DD = 1024;  // hidden dim

__device__ __forceinline__ unsigned short f32_to_bf16(float f) {
  union { float f; unsigned int u; } v;
  v.f = f;
  unsigned int r = v.u + 0x7FFFu + ((v.u >> 16) & 1u);  // RNE
  return (unsigned short)(r >> 16);
}

// ---------------------------------------------------------------------------
// Kernel 1: convert Wx (= W[:, :1024]) to bf16, transposed, in MFMA B-fragment
// order. Fragment block (kc, nb): 64 lanes x 8 bf16; value (lane, j) =
// Wx[n = nb*16 + (lane&15)][k = kc*32 + (lane>>4)*8 + j].
// ---------------------------------------------------------------------------
__global__ void prep_wxt(const float* __restrict__ W,
                         unsigned short* __restrict__ wxt) {
  int s = blockIdx.x * 256 + threadIdx.x;   // 131072 slots
  int lane = s & 63;
  int blk = s >> 6;                         // kc*64 + nb
  int nb = blk & 63;
  int kc = blk >> 6;
  int n = nb * 16 + (lane & 15);
  int k = kc * 32 + (lane >> 4) * 8;
  const float* src = W + (size_t)n * 2048 + k;
  short8 v;
#pragma unroll
  for (int j = 0; j < 8; ++j) v[j] = (short)f32_to_bf16(src[j]);
  *reinterpret_cast<short8*>(wxt + (size_t)s * 8) = v;
}

// ---------------------------------------------------------------------------
// Kernel 2: Z[b,t,d] = x[t,b,:] @ Wx[d,:] + bias[d], written into d_out.
// 128x128 tile, BK=32, 4 waves each computing 64x64 via 16x16x32 bf16 MFMA.
// A (x, fp32) is converted to bf16 during LDS staging; B comes pre-swizzled
// from prep_wxt so both fragment loads are conflict-free ds_read_b128.
// ---------------------------------------------------------------------------
__global__ __launch_bounds__(256, 2) void gemm_z(
    const float* __restrict__ x, const unsigned short* __restrict__ wxt,
    const float* __restrict__ bias, float* __restrict__ out) {
  __shared__ unsigned short Alds[8 * 512];  // 8 KB, fragment-ordered
  __shared__ unsigned short Blds[8 * 512];  // 8 KB, fragment-ordered

  int tid = threadIdx.x;
  int bx = blockIdx.x;
  int mtile = bx & 511;                     // 512 m-tiles (M = 65536)
  int ntile = bx >> 9;                      // 8 n-tiles  (N = 1024)
  int m0 = mtile * 128;
  int lane = tid & 63, w = tid >> 6;
  int mw = (w & 1) * 64, nw = (w >> 1) * 64;

  const float4* xf4 = reinterpret_cast<const float4*>(x);
  floatx4 acc[4][4] = {};

  for (int kt = 0; kt < 32; ++kt) {
    __syncthreads();
    // --- stage A: 128 rows x 32 k fp32 -> bf16 fragment layout ---
#pragma unroll
    for (int i = 0; i < 4; ++i) {
      int idx = i * 256 + tid;              // 0..1023 over (m_loc:128, kk:8)
      int m_loc = idx >> 3;
      int kk = idx & 7;                     // float4 index within 32-k chunk
      float4 xv = xf4[(size_t)(m0 + m_loc) * 256 + kt * 8 + kk];
      int l = (kk >> 1) * 16 + (m_loc & 15);
      int off = (m_loc >> 4) * 512 + l * 8 + (kk & 1) * 4;
      ushort4 pk;
      pk.x = f32_to_bf16(xv.x);
      pk.y = f32_to_bf16(xv.y);
      pk.z = f32_to_bf16(xv.z);
      pk.w = f32_to_bf16(xv.w);
      *reinterpret_cast<ushort4*>(Alds + off) = pk;
    }
    // --- stage B: 8 fragment blocks of 1 KB, already bf16+swizzled ---
#pragma unroll
    for (int i = 0; i < 2; ++i) {
      int s = i * 256 + tid;
      int nb = s >> 6;
      int ln = s & 63;
      short8 v = *reinterpret_cast<const short8*>(
          wxt + ((size_t)(kt * 64 + ntile * 8 + nb) * 512 + ln * 8));
      *reinterpret_cast<short8*>(Blds + nb * 512 + ln * 8) = v;
    }
    __syncthreads();
    // --- compute: 16 MFMA per wave per K-tile ---
    int abase = (mw >> 4) * 512 + lane * 8;
    int bbase = (nw >> 4) * 512 + lane * 8;
    short8 bf[4];
#pragma unroll
    for (int nt = 0; nt < 4; ++nt)
      bf[nt] = *reinterpret_cast<const short8*>(Blds + bbase + nt * 512);
#pragma unroll
    for (int mt = 0; mt < 4; ++mt) {
      short8 af = *reinterpret_cast<const short8*>(Alds + abase + mt * 512);
#pragma unroll
      for (int nt = 0; nt < 4; ++nt)
        acc[mt][nt] =
            __builtin_amdgcn_mfma_f32_16x16x32_bf16(af, bf[nt], acc[mt][nt], 0, 0, 0);
    }
  }

  // --- epilogue: + bias, write Z to d_out[b*T*D + t*D + d] (m = t*B + b) ---
  int quad = lane >> 4;
#pragma unroll
  for (int nt = 0; nt < 4; ++nt) {
    int n = ntile * 128 + nw + nt * 16 + (lane & 15);
    float bv = bias[n];
#pragma unroll
    for (int mt = 0; mt < 4; ++mt) {
#pragma unroll
      for (int r = 0; r < 4; ++r) {
        int m = m0 + mw + mt * 16 + quad * 4 + r;
        int t = m >> 8;
        int b = m & 255;
        out[(size_t)b * (TT * DD) + (size_t)t * DD + n] = acc[mt][nt][r] + bv;
      }
    }
  }
}

// ---------------------------------------------------------------------------
// Kernel 3: recurrence. 256 wgs (1/CU), wg g: bg = g&7 (32 batch rows),
// ng = g>>3 (32 output dims). Wh slice (32x1024 bf16 = 64 KB) lives in LDS in
// B-fragment order. Each step: h_new = tanh(Z + h_prev @ Wh.T), h exchanged
// via bf16 double buffer in ws; sync among the 32 wgs sharing bg via
// device-scope atomic counter barrier.
// ---------------------------------------------------------------------------
__global__ __launch_bounds__(256, 1) void rnn_rec(
    const float* __restrict__ W, float* __restrict__ out,
    unsigned short* __restrict__ hbuf, unsigned int* __restrict__ ctrs) {
  __shared__ unsigned short Wlds[64 * 512];  // exactly 64 KB

  int tid = threadIdx.x;
  int g = blockIdx.x;
  int bg = g & 7;     // barrier-group members share XCD under %8 round-robin
  int ng = g >> 3;

  // one-time: load Wh slice -> bf16 -> LDS in fragment order
#pragma unroll
  for (int i = 0; i < 16; ++i) {
    int s = i * 256 + tid;       // 4096 slots of 16 B
    int ln = s & 63;
    int blk = s >> 6;            // nt*32 + kc
    int nt = blk >> 5, kc = blk & 31;
    int n = ng * 32 + nt * 16 + (ln & 15);
    int k = kc * 32 + (ln >> 4) * 8;
    const float* src = W + (size_t)n * 2048 + 1024 + k;
    short8 v;
#pragma unroll
    for (int j = 0; j < 8; ++j) v[j] = (short)f32_to_bf16(src[j]);
    *reinterpret_cast<short8*>(Wlds + blk * 512 + ln * 8) = v;
  }
  __syncthreads();

  int lane = tid & 63, w = tid >> 6;
  int mt = w & 1, nt = w >> 1;           // 2x2 16x16 tiles, one per wave
  int quad = lane >> 4;
  int n_g = ng * 32 + nt * 16 + (lane & 15);
  unsigned int* ctr = ctrs + bg * 64;    // 256 B apart
  unsigned int target = 0;

  for (int t = 0; t < TT; ++t) {
    // prefetch Z (written by gemm_z into d_out) early to overlap with GEMM
    size_t zb = (size_t)(bg * 32 + mt * 16 + quad * 4) * (TT * DD) +
                (size_t)t * DD + n_g;
    float z[4];
#pragma unroll
    for (int r = 0; r < 4; ++r) z[r] = out[zb + (size_t)r * (TT * DD)];

    floatx4 acc = {0.f, 0.f, 0.f, 0.f};
    if (t > 0) {
      const unsigned short* hprev = hbuf + (size_t)((t - 1) & 1) * (BB * DD);
      const short8* ab = reinterpret_cast<const short8*>(
          hprev + (size_t)(bg * 32 + mt * 16 + (lane & 15)) * DD + quad * 8);
#pragma unroll 8
      for (int kc = 0; kc < 32; ++kc) {
        short8 af = ab[kc * 4];
        short8 bf = *reinterpret_cast<const short8*>(Wlds + (nt * 32 + kc) * 512 + lane * 8);
        acc = __builtin_amdgcn_mfma_f32_16x16x32_bf16(af, bf, acc, 0, 0, 0);
      }
    }

    // epilogue: tanh, write fp32 h to d_out (in place over Z), bf16 h to hbuf
    unsigned short* hcur = hbuf + (size_t)(t & 1) * (BB * DD);
#pragma unroll
    for (int r = 0; r < 4; ++r) {
      float v = tanhf(acc[r] + z[r]);
      out[zb + (size_t)r * (TT * DD)] = v;
      hcur[(size_t)(bg * 32 + mt * 16 + quad * 4 + r) * DD + n_g] = f32_to_bf16(v);
    }

    // sub-group barrier (32 wgs sharing bg): release -> arrive -> spin -> acquire
    target += 32;
    __threadfence();             // release: make this thread's h stores visible
    __syncthreads();             // all threads of wg fenced
    if (tid == 0) {
      __hip_atomic_fetch_add(ctr, 1u, __ATOMIC_RELEASE, __HIP_MEMORY_SCOPE_AGENT);
      while (__hip_atomic_load(ctr, __ATOMIC_RELAXED, __HIP_MEMORY_SCOPE_AGENT) < target) {
        __builtin_amdgcn_s_sleep(2);
      }
    }
    __syncthreads();
    __threadfence();             // acquire: drop stale cached h lines
  }
}

extern "C" void kernel_launch(void* const* d_in, const int* in_sizes, int n_in,
                              void* d_out, int out_size, void* d_ws, size_t ws_size,
                              hipStream_t stream) {
  (void)in_sizes; (void)n_in; (void)out_size; (void)ws_size;
  const float* x = (const float*)d_in[0];
  const float* W = (const float*)d_in[1];
  const float* b = (const float*)d_in[2];
  float* out = (float*)d_out;
  char* ws = (char*)d_ws;

  unsigned short* wxt  = (unsigned short*)ws;                        // 2 MB
  unsigned short* hbuf = (unsigned short*)(ws + (size_t)(2u << 20)); // 1 MB (2 x 512 KB)
  unsigned int*   ctrs = (unsigned int*)(ws + (size_t)(3u << 20));   // 2 KB

  hipMemsetAsync(ctrs, 0, 8 * 256, stream);  // ws is poisoned 0xAA each call
  hipLaunchKernelGGL(prep_wxt, dim3(512), dim3(256), 0, stream, W, wxt);
  hipLaunchKernelGGL(gemm_z, dim3(4096), dim3(256), 0, stream, x, wxt, b, out);

  void* args[] = {(void*)&W, (void*)&out, (void*)&hbuf, (void*)&ctrs};
  hipLaunchCooperativeKernel((void*)rnn_rec, dim3(256), dim3(256), args, 0, stream);
}